// Round 11
// baseline (730.038 us; speedup 1.0000x reference)
//
#include <hip/hip_runtime.h>
#include <hip/hip_bf16.h>

#define EPSV 1e-5f

typedef _Float16 f16x2 __attribute__((ext_vector_type(2)));
typedef short bf16x8 __attribute__((ext_vector_type(8)));
typedef float f32x4 __attribute__((ext_vector_type(4)));
typedef unsigned long long ull;

// ---------------- workspace layout (float offsets) ----------------
static constexpr long O_WHT = 1024;                  // scan Wh f16-pairs: 225000 uints
static constexpr long O_WTT = O_WHT + 225000;        // scan Wt f16-pairs: 135000 uints
static constexpr long O_W1NT= O_WTT + 135000;        // f32 [900][300]
static constexpr long O_W1RT= O_W1NT + 270000;       // f32 [900][300]
static constexpr long O_WNB = O_W1RT + 270000;       // bf16 2x[300][600]
static constexpr long O_W1B = O_WNB + 180000;        // bf16 2x[300][912] (3x304 sub)
static constexpr long O_XG  = O_W1B + 273600;        // f32 [800][1500]
static constexpr long O_PUB = O_XG + 1200000;        // seq-embedded ulongs:
//   cs64 [8][1504] ulong = 24064 f;  (unused gap);  c64 [8][304]
static constexpr long O_H64 = O_PUB + 24064;
static constexpr long O_C64 = O_H64 + 4864;
static constexpr long PUBSZ = 33792;
static constexpr long O_HN2 = O_PUB + PUBSZ;         // bf16 [800][320]
static constexpr long O_HR2 = O_HN2 + 128000;
static constexpr long O_HS2 = O_HR2 + 128000;
static constexpr long O_AU  = O_HS2 + 128000;        // f32 [2][800][300]
static constexpr long O_BU  = O_AU + 480000;
static constexpr long O_MASK= O_BU + 480000;         // [100][8]
static constexpr long O_BI  = O_MASK + 800;          // 1500 (unused, kept)
static constexpr long O_BH  = O_BI + 1504;           // 1500
static constexpr long O_BT  = O_BH + 1504;           // 300
static constexpr long O_BN  = O_BT + 304;
static constexpr long O_B1N = O_BN + 304;
static constexpr long O_GN  = O_B1N + 304;
static constexpr long O_BEN = O_GN + 304;
static constexpr long O_W2N = O_BEN + 304;           // [8][300]
static constexpr long O_B2N = O_W2N + 2400;          // 8
static constexpr long O_BR  = O_B2N + 16;
static constexpr long O_B1R = O_BR + 304;
static constexpr long O_GR  = O_B1R + 304;
static constexpr long O_BER = O_GR + 304;
static constexpr long O_W2R = O_BER + 304;           // [12][300]
static constexpr long O_B2R = O_W2R + 3600;          // 12
static constexpr long O_W2NT= O_B2R + 16;            // [300][8]
static constexpr long O_GBEN= O_W2NT + 2400;         // [300][2]
static constexpr long O_W2RT= O_GBEN + 608;          // [300][12]
static constexpr long O_GBER= O_W2RT + 3600;         // [300][2]
static constexpr long O_PRE = O_GBER + 608;          // premax keys [2][8][300] uint

__device__ __forceinline__ int is_f32(const void* mask) {
  return *((const unsigned*)mask) == 0x3F800000u;    // f32 1.0f vs bf16 {1,1}=0x3F803F80
}
__device__ __forceinline__ float ldin(const void* p, long i, int f32) {
  if (f32) return ((const float*)p)[i];
  unsigned int w = ((unsigned int)(((const unsigned short*)p)[i])) << 16;
  return __uint_as_float(w);
}
__device__ __forceinline__ unsigned short inbitsb(const void* p, long i, int f32) {
  if (!f32) return ((const unsigned short*)p)[i];
  __hip_bfloat16 hb = __float2bfloat16(((const float*)p)[i]);
  return *reinterpret_cast<unsigned short*>(&hb);
}
__device__ __forceinline__ unsigned short bfbits(float v) {
  __hip_bfloat16 hb = __float2bfloat16(v);
  return *reinterpret_cast<unsigned short*>(&hb);
}
__device__ __forceinline__ void stout(void* p, long i, float v, int f32) {
  if (f32) ((float*)p)[i] = v;
  else ((__hip_bfloat16*)p)[i] = __float2bfloat16(v);
}
__device__ __forceinline__ unsigned packf16(float a, float b) {
  union { _Float16 h[2]; unsigned u; } x;
  x.h[0] = (_Float16)a; x.h[1] = (_Float16)b;
  return x.u;
}
__device__ __forceinline__ float dot2(unsigned wu, unsigned xu, float acc) {
  return __builtin_amdgcn_fdot2(__builtin_bit_cast(f16x2, wu),
                                __builtin_bit_cast(f16x2, xu), acc, false);
}
// load 8 consecutive elements as bf16x8 from bf16 or f32 source
__device__ __forceinline__ bf16x8 ld8(const void* p, long i, int f32) {
  if (!f32) return *(const bf16x8*)((const unsigned short*)p + i);
  const float* fp = (const float*)p + i;
  bf16x8 r;
#pragma unroll
  for (int j = 0; j < 8; ++j) r[j] = (short)bfbits(fp[j]);
  return r;
}
// monotone float->uint key for atomicMax
__device__ __forceinline__ unsigned fkey(float f) {
  unsigned b = __float_as_uint(f);
  return (b & 0x80000000u) ? ~b : (b | 0x80000000u);
}
__device__ __forceinline__ float funkey(unsigned u) {
  unsigned b = (u & 0x80000000u) ? (u & 0x7FFFFFFFu) : ~u;
  return __uint_as_float(b);
}

// ---- seq-embedded MALL exchange: one 8B relaxed atomic = (f32 bits <<32) | seq ----
__device__ __forceinline__ void pub64(ull* p, float v, unsigned seq) {
  ull w = ((ull)__float_as_uint(v) << 32) | (ull)seq;
  __hip_atomic_store(p, w, __ATOMIC_RELAXED, __HIP_MEMORY_SCOPE_AGENT);
}
__device__ __forceinline__ ull ld64(const ull* p) {
  return __hip_atomic_load(p, __ATOMIC_RELAXED, __HIP_MEMORY_SCOPE_AGENT);
}
__device__ __forceinline__ float val64(ull w) {
  return __uint_as_float((unsigned)(w >> 32));
}

// ---------------- prep + xg fused: 1024 stride + 580 transpose + 300 xg blocks ----------------
__global__ __launch_bounds__(256) void k_prep(float* ws, const void* mask,
    const void* x, const void* wi, const void* wh, const void* wt,
    const void* wn, const void* wr, const void* w1n, const void* w1r,
    const void* bi, const void* bh, const void* bt,
    const void* bn, const void* b1n, const void* gn, const void* ben,
    const void* w2n, const void* b2n, const void* br, const void* b1r,
    const void* gr, const void* ber, const void* w2r, const void* b2r) {
  const int f32 = is_f32(mask);
  const int blk = blockIdx.x, t = threadIdx.x;

  if (blk >= 1604) {                      // ---- xg via MFMA, inputs read directly ----
    const int bxg = blk - 1604;           // 0..299
    const int m0 = (bxg % 50) * 16;
    const int w = t >> 6, lane = t & 63;
    const int n0 = (bxg / 50) * 256 + w * 64;
    const int rA = lane & 15, kq = (lane >> 4) * 8;
    f32x4 acc[4] = {};
    for (int kt = 0; kt < 24; ++kt) {
      bf16x8 af = ld8(x, (long)(m0 + rA) * 768 + kq + kt * 32, f32);
#pragma unroll
      for (int nf = 0; nf < 4; ++nf) {
        int rB = n0 + nf * 16 + rA;
        if (rB > 1499) rB = 1499;          // clamp: raw input has exactly 1500 rows
        bf16x8 bfv = ld8(wi, (long)rB * 768 + kq + kt * 32, f32);
        acc[nf] = __builtin_amdgcn_mfma_f32_16x16x32_bf16(af, bfv, acc[nf], 0, 0, 0);
      }
    }
    const int rD = m0 + (lane >> 4) * 4, cD = lane & 15;
#pragma unroll
    for (int nf = 0; nf < 4; ++nf) {
      int col = n0 + nf * 16 + cD;
      if (col < 1500) {
        float bv = ldin(bi, col, f32);
#pragma unroll
        for (int q = 0; q < 4; ++q)
          ws[O_XG + (long)(rD + q) * 1500 + col] = acc[nf][q] + bv;
      }
    }
    return;
  }
  if (blk >= 1024) {                      // ---- W1 f32 transposes (580 tiles) ----
    __shared__ float ts[32][33];
    int tile = blk - 1024;
    int m = tile >= 290; int ti = tile - m * 290;
    const void* src = m ? w1r : w1n;
    const long D = m ? O_W1RT : O_W1NT;
    const int R = 300, C = 900;
    int tr = ti / 29, tc = ti % 29;
    int r0 = tr * 32, c0 = tc * 32;
    const int tx = t & 31, ty = t >> 5;
#pragma unroll
    for (int k = 0; k < 4; k++) {
      int r = r0 + ty + 8 * k, c = c0 + tx;
      ts[ty + 8 * k][tx] = (r < R && c < C) ? ldin(src, (long)r * C + c, f32) : 0.f;
    }
    __syncthreads();
#pragma unroll
    for (int k = 0; k < 4; k++) {
      int c = c0 + ty + 8 * k, r = r0 + tx;
      if (c < C && r < R) ws[D + (long)c * R + r] = ts[tx][ty + 8 * k];
    }
    return;
  }

  // ---- grid-stride flat: S0 pack | S1 misc + pub/premax zero | S2 WNB/W1B ----
  for (long i = (long)blk * 256 + t; i < 1325512L; i += 1024L * 256) {
    if (i < 360000) {                     // S0: scan-weight f16-pair pack
      long q = i;
      if (q < 225000) {
        int g = q / 45000, r = q % 45000;
        int hh = r / 22500, r2 = r % 22500;
        int ii = r2 / 450, tt = r2 % 450;
        int o2 = tt % 150, kc = tt / 150;
        int row = g * 300 + 2 * o2 + hh;
        int k0 = 2 * (kc * 50 + ii);
        float lo = ldin(wh, (long)row * 300 + k0, f32);
        float hi = ldin(wh, (long)row * 300 + k0 + 1, f32);
        ((unsigned*)(ws + O_WHT))[q] = packf16(lo, hi);
      } else {
        long q2 = q - 225000;
        int g = q2 / 27000, r = q2 % 27000;
        int hh = r / 13500, r2 = r % 13500;
        int j = r2 / 450, tt = r2 % 450;
        int o2 = tt % 30, kc = tt / 30;
        int row = g * 60 + 2 * o2 + hh;
        int k0 = 2 * (kc * 30 + j);
        float lo = ldin(wt, (long)row * 900 + k0, f32);
        float hi = ldin(wt, (long)row * 900 + k0 + 1, f32);
        ((unsigned*)(ws + O_WTT))[q2] = packf16(lo, hi);
      }
      continue;
    }
    if (i < 418312) {                     // S1: misc + pub zero + premax zero
      long idx = i - 360000;
      if (idx >= 53512) { ws[O_PRE + (idx - 53512)] = 0.f; continue; }   // premax keys = 0
      if (idx >= 19720) { ws[O_PUB + (idx - 19720)] = 0.f; continue; }
      const void* s; long d; float v;
      if (idx < 800)                   { s = mask; d = O_MASK; }
      else if ((idx -= 800) < 1500)    { s = bi;  d = O_BI; }
      else if ((idx -= 1500) < 1500)   { s = bh;  d = O_BH; }
      else if ((idx -= 1500) < 300)    { s = bt;  d = O_BT; }
      else if ((idx -= 300) < 300)     { s = bn;  d = O_BN; }
      else if ((idx -= 300) < 300)     { s = b1n; d = O_B1N; }
      else if ((idx -= 300) < 300)     { s = gn;  d = O_GN; }
      else if ((idx -= 300) < 300)     { s = ben; d = O_BEN; }
      else if ((idx -= 300) < 2400)    { s = w2n; d = O_W2N; }
      else if ((idx -= 2400) < 8)      { s = b2n; d = O_B2N; }
      else if ((idx -= 8) < 300)       { s = br;  d = O_BR; }
      else if ((idx -= 300) < 300)     { s = b1r; d = O_B1R; }
      else if ((idx -= 300) < 300)     { s = gr;  d = O_GR; }
      else if ((idx -= 300) < 300)     { s = ber; d = O_BER; }
      else if ((idx -= 300) < 3600)    { s = w2r; d = O_W2R; }
      else if ((idx -= 3600) < 12)     { s = b2r; d = O_B2R; }
      else if ((idx -= 12) < 2400) {   // W2NT [300][8]
        int o = idx >> 3, q = idx & 7;
        ws[O_W2NT + idx] = ldin(w2n, (long)q * 300 + o, f32);
        continue;
      }
      else if ((idx -= 2400) < 600) {  // GBEN [300][2]
        int o = idx >> 1;
        ws[O_GBEN + idx] = ldin((idx & 1) ? ben : gn, o, f32);
        continue;
      }
      else if ((idx -= 600) < 3600) {  // W2RT [300][12]
        int o = idx / 12, q = idx % 12;
        ws[O_W2RT + idx] = ldin(w2r, (long)q * 300 + o, f32);
        continue;
      }
      else {                           // GBER [300][2]
        idx -= 3600;
        int o = idx >> 1;
        ws[O_GBER + idx] = ldin((idx & 1) ? ber : gr, o, f32);
        continue;
      }
      v = ldin(s, idx, f32);
      ws[d + idx] = v;
      continue;
    }
    // S2: WNB / W1B bf16 operand fill
    long idx = i - 418312;
    if (idx < 360000) {
      int u = idx / 180000; long r = idx % 180000;
      ((unsigned short*)(ws + O_WNB))[idx] = inbitsb(u ? wr : wn, r, f32);
    } else {
      long r2 = idx - 360000;              // 2 x [300][912], 3x304 k-sub-blocks
      int u = r2 / 273600; long rr = r2 % 273600;
      int n = rr / 912, kk = rr % 912;
      int p = kk / 304, k = kk - p * 304;
      unsigned short v = 0;
      if (k < 300) v = inbitsb(u ? w1r : w1n, (long)n * 900 + p * 300 + k, f32);
      ((unsigned short*)(ws + O_W1B))[r2] = v;
    }
  }
}

// ---------------- the recurrent scan: 40 WGs, concurrent-batched seq-sync (frozen R9) ----------------
__global__ __launch_bounds__(512, 2) void k_scan(float* ws) {
  const int w = blockIdx.x;            // 40
  const int b = w & 7, g = w >> 3;     // batch, gate-group/output-slice
  const int t = threadIdx.x;
  const int lane = t & 63, wid = t >> 6;
  const unsigned* W1 = (const unsigned*)(ws + O_WHT) + g * 45000;
  const unsigned* W2 = (const unsigned*)(ws + O_WTT) + g * 27000;
  const float* xg = ws + O_XG;
  ull* cs64 = (ull*)(ws + O_PUB) + (long)b * 1504;
  ull* c64  = (ull*)(ws + O_C64) + (long)b * 304;
  unsigned short* HN2 = (unsigned short*)(ws + O_HN2);
  unsigned short* HR2 = (unsigned short*)(ws + O_HR2);
  unsigned short* HS2 = (unsigned short*)(ws + O_HS2);

  // persistent weights in registers (f16 pairs along k)
  unsigned wA0[50], wA1[50], wB0[30], wB1[30];
  if (t < 450) {
#pragma unroll
    for (int i = 0; i < 50; ++i) { wA0[i] = W1[i * 450 + t]; wA1[i] = W1[22500 + i * 450 + t]; }
#pragma unroll
    for (int j = 0; j < 30; ++j) { wB0[j] = W2[j * 450 + t]; wB1[j] = W2[13500 + j * 450 + t]; }
  }
  // loop-invariant bias prefetch
  const float bhv = (t < 300) ? ws[O_BH + g * 300 + t] : 0.f;
  const float btv = (t < 60) ? ws[O_BT + g * 60 + t] : 0.f;

  __shared__ __align__(16) unsigned h2[152];     // h as f16 pairs
  __shared__ __align__(16) float cf[304];        // c(l-1) f32
  __shared__ __align__(16) float cfown[64];      // own c slice (skip self-poll)
  __shared__ __align__(16) float gatef[304];
  __shared__ __align__(16) float pacc[3][304];
  __shared__ __align__(16) float csL[1504];
  __shared__ __align__(16) float catf[912];
  __shared__ __align__(16) unsigned cat2[456];
  __shared__ __align__(16) float pacc2[15][64];

  if (t < 64) cfown[t] = 0.f;
  __syncthreads();

  const int o2a = t % 150, kca = t / 150;        // phase-A tile
  const int o2b = t % 30,  kcb = t / 30;         // phase-B tile

  for (int l = 0; l < 100; ++l) {
    const unsigned sl = (unsigned)l, sn = (unsigned)(l + 1);
    // prefetch xg early (L3 latency hides under the c-gather poll)
    float xgv = (t < 300) ? xg[((long)l * 8 + b) * 1500 + g * 300 + t] : 0.f;

    // ---- gather c(l-1): 150 threads, 2 CONCURRENT polls each; h=tanh(c) local ----
    if (t < 150) {
      const int ia = 2 * t;
      float va, vb;
      if (ia / 60 == g) {                        // own slice from LDS
        va = cfown[ia - g * 60]; vb = cfown[ia + 1 - g * 60];
      } else {
        ull wa = ld64(c64 + ia), wb = ld64(c64 + ia + 1);
        long it = 0;
        while ((((unsigned)wa != sl) || ((unsigned)wb != sl)) && ++it < (1L << 22)) {
          if ((unsigned)wa != sl) wa = ld64(c64 + ia);
          if ((unsigned)wb != sl) wb = ld64(c64 + ia + 1);
        }
        va = val64(wa); vb = val64(wb);
      }
      cf[ia] = va; cf[ia + 1] = vb;
      h2[t] = packf16(tanhf(va), tanhf(vb));
    }
    __syncthreads();

    // ---- phase A: gate slice = Wh_g@h + xg + bh; cumsoftmax; publish cs (seq l+1) ----
    if (t < 450) {
      float a0 = 0.f, a1 = 0.f;
      const unsigned* hp = h2 + kca * 50;
#pragma unroll
      for (int i = 0; i < 50; ++i) {
        unsigned hv = hp[i];
        a0 = dot2(wA0[i], hv, a0);
        a1 = dot2(wA1[i], hv, a1);
      }
      pacc[kca][2 * o2a] = a0; pacc[kca][2 * o2a + 1] = a1;
    }
    __syncthreads();
    if (t < 300)
      gatef[t] = pacc[0][t] + pacc[1][t] + pacc[2][t] + xgv + bhv;
    __syncthreads();
    if (g == 0) {
      if (t < 300) {
        float v = tanhf(gatef[t]);
        csL[t] = v;
        pub64(cs64 + t, v, sn);
      }
    } else if (wid == 0) {
      const int base = lane * 5;
      float e0 = 0.f, e1 = 0.f, e2 = 0.f, e3 = 0.f, e4 = 0.f, m = -3.0e38f;
      if (lane < 60) {
        e0 = gatef[base]; e1 = gatef[base + 1]; e2 = gatef[base + 2];
        e3 = gatef[base + 3]; e4 = gatef[base + 4];
        m = fmaxf(fmaxf(fmaxf(e0, e1), fmaxf(e2, e3)), e4);
      }
#pragma unroll
      for (int of = 32; of >= 1; of >>= 1) m = fmaxf(m, __shfl_xor(m, of, 64));
      float s0 = 0.f, s1 = 0.f, s2 = 0.f, s3 = 0.f, s4 = 0.f, tot = 0.f;
      if (lane < 60) {
        e0 = __expf(e0 - m); e1 = __expf(e1 - m); e2 = __expf(e2 - m);
        e3 = __expf(e3 - m); e4 = __expf(e4 - m);
        s0 = e0; s1 = s0 + e1; s2 = s1 + e2; s3 = s2 + e3; s4 = s3 + e4;
        tot = s4;
      }
      float sc = tot;
#pragma unroll
      for (int of = 1; of < 64; of <<= 1) {
        float u = __shfl_up(sc, of, 64);
        if (lane >= of) sc += u;
      }
      float total = __shfl(sc, 63);
      if (lane < 60) {
        float ex = sc - tot, inv = 1.f / total;
        float v0 = (ex + s0) * inv, v1 = (ex + s1) * inv, v2 = (ex + s2) * inv;
        float v3 = (ex + s3) * inv, v4 = (ex + s4) * inv;
        const int o0 = g * 300 + base;
        csL[o0] = v0; csL[o0 + 1] = v1; csL[o0 + 2] = v2; csL[o0 + 3] = v3; csL[o0 + 4] = v4;
        pub64(cs64 + o0 + 0, v0, sn);
        pub64(cs64 + o0 + 1, v1, sn);
        pub64(cs64 + o0 + 2, v2, sn);
        pub64(cs64 + o0 + 3, v3, sn);
        pub64(cs64 + o0 + 4, v4, sn);
      }
    }

    // ---- phase B: gather foreign cs with 3 CONCURRENT polls per thread ----
    {
      const int i0 = t, i1 = t + 512, i2 = t + 1024;
      const bool n0 = (i0 / 300) != g;
      const bool n1 = (i1 < 1500) && ((i1 / 300) != g);
      const bool n2 = (i2 < 1500) && ((i2 / 300) != g);
      ull w0 = n0 ? ld64(cs64 + i0) : 0;
      ull w1 = n1 ? ld64(cs64 + i1) : 0;
      ull w2 = n2 ? ld64(cs64 + i2) : 0;
      long it = 0;
      for (;;) {
        bool s0 = n0 && (unsigned)w0 != sn;
        bool s1 = n1 && (unsigned)w1 != sn;
        bool s2 = n2 && (unsigned)w2 != sn;
        if (!(s0 || s1 || s2) || ++it > (1L << 22)) break;
        if (s0) w0 = ld64(cs64 + i0);
        if (s1) w1 = ld64(cs64 + i1);
        if (s2) w2 = ld64(cs64 + i2);
      }
      if (n0) csL[i0] = val64(w0);
      if (n1) csL[i1] = val64(w1);
      if (n2) csL[i2] = val64(w2);
    }
    __syncthreads();
    if (t < 300) {
      float cgv = csL[t];
      float egi = 1.f - csL[300 + t];
      float rgi = csL[600 + t];
      float egc = 1.f - csL[900 + t];
      float rgc = csL[1200 + t];
      float cin = cf[t];
      float ovc = rgc * egc, upc = rgc - ovc, dnc = egc - ovc;
      float ovi = rgi * egi, upi = rgi - ovi, dni = egi - ovi;
      float sh = ovi * cin + ovc * cgv;
      float cre = upi * cin + upc * cgv + sh;
      float cner = dni * cin + dnc * cgv + sh;
      catf[t] = cre; catf[300 + t] = cner; catf[600 + t] = sh;
      if (g == 0) {
        long rb = ((long)l * 8 + b) * 320;
        HN2[rb + t] = bfbits(tanhf(cner));
        HR2[rb + t] = bfbits(tanhf(cre));
        HS2[rb + t] = bfbits(tanhf(sh));
      }
    } else if (g == 0 && t < 320) {
      long rb = ((long)l * 8 + b) * 320;
      HN2[rb + t] = 0; HR2[rb + t] = 0; HS2[rb + t] = 0;
    }
    __syncthreads();
    if (t < 450) cat2[t] = packf16(catf[2 * t], catf[2 * t + 1]);
    __syncthreads();
    if (t < 450) {
      float a0 = 0.f, a1 = 0.f;
      const unsigned* cp = cat2 + kcb * 30;
#pragma unroll
      for (int j = 0; j < 30; ++j) {
        unsigned cv = cp[j];
        a0 = dot2(wB0[j], cv, a0);
        a1 = dot2(wB1[j], cv, a1);
      }
      pacc2[kcb][2 * o2b] = a0; pacc2[kcb][2 * o2b + 1] = a1;
    }
    __syncthreads();
    if (t < 60) {
      float s = btv;
#pragma unroll
      for (int kc = 0; kc < 15; ++kc) s += pacc2[kc][t];
      pub64(c64 + g * 60 + t, s, sn);    // consumers derive h = tanh(c)
      cfown[t] = s;
    }
    __syncthreads();                     // cfown LDS handoff to next-step gather
  }
}

// ---------------- merged g3a + g3c via MFMA; g3a also atomicMax premax ----------------
__global__ __launch_bounds__(256) void k_g3ac(float* ws, void* dout, const void* mask) {
  const int z = blockIdx.z;
  const int m0 = blockIdx.x * 16;
  const int w = threadIdx.x >> 6, lane = threadIdx.x & 63;
  const int n0 = blockIdx.y * 256 + w * 64;
  if (n0 >= 300) return;
  const int rA = lane & 15, kq = (lane >> 4) * 8;
  const int rD = m0 + (lane >> 4) * 4, cD = lane & 15;

  if (z < 2) {                 // ---- g3a: z-pre-activation -> premax atomics (+ dout for u=1) ----
    const int u = z;
    const int f32 = is_f32(mask);
    const unsigned short* A0 = (const unsigned short*)(ws + O_HS2);
    const unsigned short* A1 = (const unsigned short*)(ws + (u ? O_HR2 : O_HN2));
    const unsigned short* B = (const unsigned short*)(ws + O_WNB) + (long)u * 180000;
    const unsigned short* a0p = A0 + (long)(m0 + rA) * 320 + kq;
    const unsigned short* a1p = A1 + (long)(m0 + rA) * 320 + kq;
    const unsigned short* bp = B + (long)(n0 + rA) * 600 + kq;
    f32x4 acc[4] = {};
    for (int kt = 0; kt < 10; ++kt) {
      bf16x8 af = *(const bf16x8*)(a0p + kt * 32);
#pragma unroll
      for (int nf = 0; nf < 4; ++nf) {
        bf16x8 bf = *(const bf16x8*)(bp + (long)nf * 16 * 600 + kt * 32);
        acc[nf] = __builtin_amdgcn_mfma_f32_16x16x32_bf16(af, bf, acc[nf], 0, 0, 0);
      }
    }
    for (int kt = 0; kt < 10; ++kt) {
      bf16x8 af = *(const bf16x8*)(a1p + kt * 32);
#pragma unroll
      for (int nf = 0; nf < 4; ++nf) {
        bf16x8 bf = *(const bf16x8*)(bp + (long)nf * 16 * 600 + 300 + kt * 32);
        acc[nf] = __builtin_amdgcn_mfma_f32_16x16x32_bf16(af, bf, acc[nf], 0, 0, 0);
      }
    }
    unsigned* pre = (unsigned*)(ws + O_PRE) + (long)u * 2400;
#pragma unroll
    for (int nf = 0; nf < 4; ++nf) {
      int col = n0 + nf * 16 + cD;
      if (col < 300) {
        float bv = ws[(u ? O_BR : O_BN) + col];
#pragma unroll
        for (int q = 0; q < 4; ++q) {
          float zz = acc[nf][q] + bv;
          int row = rD + q;
          atomicMax(pre + (row & 7) * 300 + col, fkey(zz));
          if (u == 1)
            stout(dout, 1600000L + (long)row * 300 + col, tanhf(zz), f32);
        }
      }
    }
  } else {                     // ---- g3c: start/end token projections a,b ----
    const int u = (z - 2) >> 1, proj = (z - 2) & 1;
    const unsigned short* A = (const unsigned short*)(ws + (u ? O_HR2 : O_HN2));
    const unsigned short* B = (const unsigned short*)(ws + O_W1B) + (long)u * 273600;
    const unsigned short* ap = A + (long)(m0 + rA) * 320 + kq;
    const unsigned short* bp = B + (long)(n0 + rA) * 912 + proj * 304 + kq;
    f32x4 acc[4] = {};
    for (int kt = 0; kt < 10; ++kt) {
      bf16x8 af = *(const bf16x8*)(ap + kt * 32);
#pragma unroll
      for (int nf = 0; nf < 4; ++nf) {
        bf16x8 bf = *(const bf16x8*)(bp + (long)nf * 16 * 912 + kt * 32);
        acc[nf] = __builtin_amdgcn_mfma_f32_16x16x32_bf16(af, bf, acc[nf], 0, 0, 0);
      }
    }
    const long dst = (proj ? O_BU : O_AU) + (long)u * 240000;
#pragma unroll
    for (int nf = 0; nf < 4; ++nf) {
      int col = n0 + nf * 16 + cD;
      if (col < 300) {
#pragma unroll
        for (int q = 0; q < 4; ++q)
          ws[dst + (long)(rD + q) * 300 + col] = acc[nf][q];
      }
    }
  }
}

// ---------------- fused pair scoring (now also derives the c-projection in-block) ----------------
template <int NOUT, bool TRI>
__device__ __forceinline__ void pair_body(float* ws, void* dout, int f32, int b,
    long obase, long uofs, long w2tofs, long b2ofs, long gbeofs,
    long preofs, long w1cofs, long b1ofs,
    float* aS, float* bS, float* miS, float* mjS, float* hsL, float* cSL) {
  const int i0 = blockIdx.x * 16, j0 = blockIdx.y * 32;
  const int t = threadIdx.x;
  // prologue: hs = tanh(decode(premax)); cS = b1 + hs @ W1c  (== old k_g3b, same order)
  if (t < 300) {
    unsigned u = ((const unsigned*)(ws + preofs))[b * 300 + t];
    hsL[t] = tanhf(funkey(u));
  }
  __syncthreads();
  if (t < 300) {
    const float* w1 = ws + w1cofs;
    float a2 = ws[b1ofs + t];
#pragma unroll 4
    for (int k = 0; k < 300; ++k) a2 = fmaf(hsL[k], w1[(long)(600 + k) * 300 + t], a2);
    cSL[t] = a2;
  }
  __syncthreads();
  for (int s = t; s < 16 * 300; s += 512) {
    int r = s / 300, o = s - r * 300;
    int i = i0 + r;
    float v = 0.f;
    if (i < 100) v = ws[O_AU + uofs + ((long)i * 8 + b) * 300 + o] + cSL[o];
    aS[r * 305 + o] = v;
  }
  for (int s = t; s < 32 * 300; s += 512) {
    int r = s / 300, o = s - r * 300;
    int j = j0 + r;
    bS[r * 305 + o] = (j < 100) ? ws[O_BU + uofs + ((long)j * 8 + b) * 300 + o] : 0.f;
  }
  if (t < 16) miS[t] = (i0 + t < 100) ? ws[O_MASK + (i0 + t) * 8 + b] : 0.f;
  else if (t < 48) mjS[t - 16] = (j0 + t - 16 < 100) ? ws[O_MASK + (j0 + t - 16) * 8 + b] : 0.f;
  __syncthreads();
  const int wid = t >> 6, lane = t & 63;
  const int ii = wid * 2 + (lane >> 5);
  const int jj = lane & 31;
  const int i = i0 + ii, j = j0 + jj;
  if (i >= 100 || j >= 100) return;
  long base = obase + (((long)i * 100 + j) * 8 + b) * NOUT;
  // whole-wave lower-triangle skip (all 64 pair-slots have j < i)
  if (TRI && (j0 + 31 < i0 + wid * 2)) {
#pragma unroll
    for (int q = 0; q < NOUT; ++q) stout(dout, base + q, 0.f, f32);
    return;
  }
  const float* ap = aS + ii * 305;
  const float* bp = bS + jj * 305;
  float sum = 0.f, ssq = 0.f;
#pragma unroll 4
  for (int o = 0; o < 300; ++o) {
    float v = ap[o] + bp[o];
    sum += v;
    ssq = fmaf(v, v, ssq);
  }
  float mean = sum * (1.f / 300.f);
  float inv = rsqrtf(ssq * (1.f / 300.f) - mean * mean + EPSV);
  float acc[NOUT];
#pragma unroll
  for (int q = 0; q < NOUT; ++q) acc[q] = 0.f;
  const float* gbe = ws + gbeofs;
  const float* w2t = ws + w2tofs;
#pragma unroll 2
  for (int o = 0; o < 300; ++o) {
    float v = ap[o] + bp[o];
    float xn = fmaf((v - mean) * inv, gbe[2 * o], gbe[2 * o + 1]);
    float e = xn > 0.f ? xn : (__expf(xn) - 1.f);
#pragma unroll
    for (int q = 0; q < NOUT; ++q) acc[q] = fmaf(e, w2t[o * NOUT + q], acc[q]);
  }
  float mv = miS[ii] * mjS[jj];
  if (TRI && j < i) mv = 0.f;
#pragma unroll
  for (int q = 0; q < NOUT; ++q) {
    float b2v = ws[b2ofs + q];
    stout(dout, base + q, mv / (1.f + __expf(-(acc[q] + b2v))), f32);
  }
}

__global__ __launch_bounds__(512) void k_pairs2(float* ws, void* dout, const void* mask) {
  __shared__ float aS[16 * 305];
  __shared__ float bS[32 * 305];
  __shared__ float miS[16], mjS[32];
  __shared__ float hsL[304], cSL[304];
  const int f32 = is_f32(mask);
  const int z = blockIdx.z;
  if (z < 8)
    pair_body<8, true>(ws, dout, f32, z, 0L, 0L, O_W2NT, O_B2N, O_GBEN,
                       O_PRE, O_W1NT, O_B1N, aS, bS, miS, mjS, hsL, cSL);
  else
    pair_body<12, false>(ws, dout, f32, z - 8, 640000L, 240000L, O_W2RT, O_B2R, O_GBER,
                         O_PRE + 2400, O_W1RT, O_B1R, aS, bS, miS, mjS, hsL, cSL);
}

// ---------------- host ----------------
extern "C" void kernel_launch(void* const* d_in, const int* in_sizes, int n_in,
                              void* d_out, int out_size, void* d_ws, size_t ws_size,
                              hipStream_t stream) {
  (void)in_sizes; (void)n_in; (void)out_size; (void)ws_size;
  float* ws = (float*)d_ws;
  const void* mask = d_in[1];
  k_prep<<<dim3(1904), dim3(256), 0, stream>>>(ws, mask,
      d_in[0], d_in[2], d_in[4], d_in[6],
      d_in[8], d_in[16], d_in[10], d_in[18],
      d_in[3], d_in[5], d_in[7],
      d_in[9], d_in[11], d_in[12], d_in[13], d_in[14], d_in[15],
      d_in[17], d_in[19], d_in[20], d_in[21], d_in[22], d_in[23]);
  k_scan<<<dim3(40), dim3(512), 0, stream>>>(ws);
  k_g3ac<<<dim3(50, 2, 6), dim3(256), 0, stream>>>(ws, d_out, mask);
  k_pairs2<<<dim3(7, 4, 16), dim3(512), 0, stream>>>(ws, d_out, mask);
}

// Round 12
// 671.613 us; speedup vs baseline: 1.0870x; 1.0870x over previous
//
#include <hip/hip_runtime.h>
#include <hip/hip_bf16.h>

#define EPSV 1e-5f

typedef _Float16 f16x2 __attribute__((ext_vector_type(2)));
typedef short bf16x8 __attribute__((ext_vector_type(8)));
typedef float f32x4 __attribute__((ext_vector_type(4)));
typedef unsigned long long ull;

// ---------------- workspace layout (float offsets) ----------------
static constexpr long O_WHT = 1024;                  // scan Wh f16-pairs: 225000 uints
static constexpr long O_WTT = O_WHT + 225000;        // scan Wt f16-pairs: 135000 uints
static constexpr long O_W1NT= O_WTT + 135000;        // f32 [900][300] (g3b)
static constexpr long O_W1RT= O_W1NT + 270000;       // f32 [900][300]
static constexpr long O_XB  = O_W1RT + 270000;       // bf16 [800][768] (f32 fallback only)
static constexpr long O_WIB = O_XB + 307200;         // bf16 [1500][768] (f32 fallback only)
static constexpr long O_WNB = O_WIB + 576000;        // bf16 2x[300][600]
static constexpr long O_W1B = O_WNB + 180000;        // bf16 2x[300][912] (3x304 sub)
static constexpr long O_XG  = O_W1B + 273600;        // f32 [800][1500]
static constexpr long O_PUB = O_XG + 1200000;        // seq-embedded ulongs:
//   cs64 [8][1504] ulong = 24064 f;  (h64 slot unused);  c64 [8][304]
static constexpr long O_H64 = O_PUB + 24064;
static constexpr long O_C64 = O_H64 + 4864;
static constexpr long PUBSZ = 33792;
static constexpr long O_HN2 = O_PUB + PUBSZ;         // bf16 [800][320]
static constexpr long O_HR2 = O_HN2 + 128000;
static constexpr long O_HS2 = O_HR2 + 128000;
static constexpr long O_TG  = O_HS2 + 128000;        // f32 [2][800][300]
static constexpr long O_AU  = O_TG + 480000;         // f32 [2][800][300]
static constexpr long O_BU  = O_AU + 480000;
static constexpr long O_CU  = O_BU + 480000;         // f32 [2][8][300]
static constexpr long O_MASK= O_CU + 4800;           // [100][8]
static constexpr long O_BI  = O_MASK + 800;          // 1500
static constexpr long O_BH  = O_BI + 1504;           // 1500
static constexpr long O_BT  = O_BH + 1504;           // 300
static constexpr long O_BN  = O_BT + 304;
static constexpr long O_B1N = O_BN + 304;
static constexpr long O_GN  = O_B1N + 304;
static constexpr long O_BEN = O_GN + 304;
static constexpr long O_W2N = O_BEN + 304;           // [8][300]
static constexpr long O_B2N = O_W2N + 2400;          // 8
static constexpr long O_BR  = O_B2N + 16;
static constexpr long O_B1R = O_BR + 304;
static constexpr long O_GR  = O_B1R + 304;
static constexpr long O_BER = O_GR + 304;
static constexpr long O_W2R = O_BER + 304;           // [12][300]
static constexpr long O_B2R = O_W2R + 3600;          // 12
static constexpr long O_W2NT= O_B2R + 16;            // [300][8]
static constexpr long O_GBEN= O_W2NT + 2400;         // [300][2]
static constexpr long O_W2RT= O_GBEN + 608;          // [300][12]
static constexpr long O_GBER= O_W2RT + 3600;         // [300][2]

__device__ __forceinline__ int is_f32(const void* mask) {
  return *((const unsigned*)mask) == 0x3F800000u;    // f32 1.0f vs bf16 {1,1}=0x3F803F80
}
__device__ __forceinline__ float ldin(const void* p, long i, int f32) {
  if (f32) return ((const float*)p)[i];
  unsigned int w = ((unsigned int)(((const unsigned short*)p)[i])) << 16;
  return __uint_as_float(w);
}
__device__ __forceinline__ unsigned short inbitsb(const void* p, long i, int f32) {
  if (!f32) return ((const unsigned short*)p)[i];
  __hip_bfloat16 hb = __float2bfloat16(((const float*)p)[i]);
  return *reinterpret_cast<unsigned short*>(&hb);
}
__device__ __forceinline__ unsigned short bfbits(float v) {
  __hip_bfloat16 hb = __float2bfloat16(v);
  return *reinterpret_cast<unsigned short*>(&hb);
}
__device__ __forceinline__ void stout(void* p, long i, float v, int f32) {
  if (f32) ((float*)p)[i] = v;
  else ((__hip_bfloat16*)p)[i] = __float2bfloat16(v);
}
__device__ __forceinline__ unsigned packf16(float a, float b) {
  union { _Float16 h[2]; unsigned u; } x;
  x.h[0] = (_Float16)a; x.h[1] = (_Float16)b;
  return x.u;
}
__device__ __forceinline__ float dot2(unsigned wu, unsigned xu, float acc) {
  return __builtin_amdgcn_fdot2(__builtin_bit_cast(f16x2, wu),
                                __builtin_bit_cast(f16x2, xu), acc, false);
}

// ---- seq-embedded MALL exchange: one 8B relaxed atomic = (f32 bits <<32) | seq ----
__device__ __forceinline__ void pub64(ull* p, float v, unsigned seq) {
  ull w = ((ull)__float_as_uint(v) << 32) | (ull)seq;
  __hip_atomic_store(p, w, __ATOMIC_RELAXED, __HIP_MEMORY_SCOPE_AGENT);
}
__device__ __forceinline__ ull ld64(const ull* p) {
  return __hip_atomic_load(p, __ATOMIC_RELAXED, __HIP_MEMORY_SCOPE_AGENT);
}
__device__ __forceinline__ float val64(ull w) {
  return __uint_as_float((unsigned)(w >> 32));
}

// ---------------- one prep kernel, compact grid: 1024 stride blocks + 580 tiles ----------------
__global__ __launch_bounds__(256) void k_prep(float* ws, const void* mask,
    const void* x, const void* wi, const void* wh, const void* wt,
    const void* wn, const void* wr, const void* w1n, const void* w1r,
    const void* bi, const void* bh, const void* bt,
    const void* bn, const void* b1n, const void* gn, const void* ben,
    const void* w2n, const void* b2n, const void* br, const void* b1r,
    const void* gr, const void* ber, const void* w2r, const void* b2r) {
  const int f32 = is_f32(mask);
  const int blk = blockIdx.x, t = threadIdx.x;

  if (blk >= 1024) {                      // ---- W1 f32 transposes (580 tiles) ----
    __shared__ float ts[32][33];
    int tile = blk - 1024;
    int m = tile >= 290; int ti = tile - m * 290;
    const void* src = m ? w1r : w1n;
    const long D = m ? O_W1RT : O_W1NT;
    const int R = 300, C = 900;
    int tr = ti / 29, tc = ti % 29;
    int r0 = tr * 32, c0 = tc * 32;
    const int tx = t & 31, ty = t >> 5;
#pragma unroll
    for (int k = 0; k < 4; k++) {
      int r = r0 + ty + 8 * k, c = c0 + tx;
      ts[ty + 8 * k][tx] = (r < R && c < C) ? ldin(src, (long)r * C + c, f32) : 0.f;
    }
    __syncthreads();
#pragma unroll
    for (int k = 0; k < 4; k++) {
      int c = c0 + ty + 8 * k, r = r0 + tx;
      if (c < C && r < R) ws[D + (long)c * R + r] = ts[tx][ty + 8 * k];
    }
    return;
  }

  // ---- grid-stride flat work: S0 pack | S1 misc+zero | S2 WNB/W1B | S3 XB/WIB (f32 only) ----
  const long NCOPY = f32 ? 3087112L : 1320712L;
  for (long i = (long)blk * 256 + t; i < NCOPY; i += 1024L * 256) {
    if (i < 360000) {                     // S0: scan-weight f16-pair pack
      long q = i;
      if (q < 225000) {
        int g = q / 45000, r = q % 45000;
        int hh = r / 22500, r2 = r % 22500;
        int ii = r2 / 450, tt = r2 % 450;
        int o2 = tt % 150, kc = tt / 150;
        int row = g * 300 + 2 * o2 + hh;
        int k0 = 2 * (kc * 50 + ii);
        float lo = ldin(wh, (long)row * 300 + k0, f32);
        float hi = ldin(wh, (long)row * 300 + k0 + 1, f32);
        ((unsigned*)(ws + O_WHT))[q] = packf16(lo, hi);
      } else {
        long q2 = q - 225000;
        int g = q2 / 27000, r = q2 % 27000;
        int hh = r / 13500, r2 = r % 13500;
        int j = r2 / 450, tt = r2 % 450;
        int o2 = tt % 30, kc = tt / 30;
        int row = g * 60 + 2 * o2 + hh;
        int k0 = 2 * (kc * 30 + j);
        float lo = ldin(wt, (long)row * 900 + k0, f32);
        float hi = ldin(wt, (long)row * 900 + k0 + 1, f32);
        ((unsigned*)(ws + O_WTT))[q2] = packf16(lo, hi);
      }
      continue;
    }
    if (i < 413512) {                     // S1: misc biases/transposes + pub zero
      long idx = i - 360000;
      if (idx >= 19720) { ws[O_PUB + (idx - 19720)] = 0.f; continue; }
      const void* s; long d; float v;
      if (idx < 800)                   { s = mask; d = O_MASK; }
      else if ((idx -= 800) < 1500)    { s = bi;  d = O_BI; }
      else if ((idx -= 1500) < 1500)   { s = bh;  d = O_BH; }
      else if ((idx -= 1500) < 300)    { s = bt;  d = O_BT; }
      else if ((idx -= 300) < 300)     { s = bn;  d = O_BN; }
      else if ((idx -= 300) < 300)     { s = b1n; d = O_B1N; }
      else if ((idx -= 300) < 300)     { s = gn;  d = O_GN; }
      else if ((idx -= 300) < 300)     { s = ben; d = O_BEN; }
      else if ((idx -= 300) < 2400)    { s = w2n; d = O_W2N; }
      else if ((idx -= 2400) < 8)      { s = b2n; d = O_B2N; }
      else if ((idx -= 8) < 300)       { s = br;  d = O_BR; }
      else if ((idx -= 300) < 300)     { s = b1r; d = O_B1R; }
      else if ((idx -= 300) < 300)     { s = gr;  d = O_GR; }
      else if ((idx -= 300) < 300)     { s = ber; d = O_BER; }
      else if ((idx -= 300) < 3600)    { s = w2r; d = O_W2R; }
      else if ((idx -= 3600) < 12)     { s = b2r; d = O_B2R; }
      else if ((idx -= 12) < 2400) {   // W2NT [300][8]
        int o = idx >> 3, q = idx & 7;
        ws[O_W2NT + idx] = ldin(w2n, (long)q * 300 + o, f32);
        continue;
      }
      else if ((idx -= 2400) < 600) {  // GBEN [300][2]
        int o = idx >> 1;
        ws[O_GBEN + idx] = ldin((idx & 1) ? ben : gn, o, f32);
        continue;
      }
      else if ((idx -= 600) < 3600) {  // W2RT [300][12]
        int o = idx / 12, q = idx % 12;
        ws[O_W2RT + idx] = ldin(w2r, (long)q * 300 + o, f32);
        continue;
      }
      else {                           // GBER [300][2]
        idx -= 3600;
        int o = idx >> 1;
        ws[O_GBER + idx] = ldin((idx & 1) ? ber : gr, o, f32);
        continue;
      }
      v = ldin(s, idx, f32);
      ws[d + idx] = v;
      continue;
    }
    if (i < 1320712) {                    // S2: WNB / W1B bf16 operand fill
      long idx = i - 413512;
      if (idx < 360000) {
        int u = idx / 180000; long r = idx % 180000;
        ((unsigned short*)(ws + O_WNB))[idx] = inbitsb(u ? wr : wn, r, f32);
      } else {
        long r2 = idx - 360000;            // 2 x [300][912], 3x304 k-sub-blocks
        int u = r2 / 273600; long rr = r2 % 273600;
        int n = rr / 912, kk = rr % 912;
        int p = kk / 304, k = kk - p * 304;
        unsigned short v = 0;
        if (k < 300) v = inbitsb(u ? w1r : w1n, (long)n * 900 + p * 300 + k, f32);
        ((unsigned short*)(ws + O_W1B))[r2] = v;
      }
      continue;
    }
    // S3: XB / WIB conversion (reached only when f32)
    long idx = i - 1320712;
    if (idx < 614400) ((unsigned short*)(ws + O_XB))[idx] = inbitsb(x, idx, 1);
    else ((unsigned short*)(ws + O_WIB))[idx - 614400] = inbitsb(wi, idx - 614400, 1);
  }
}

// ---------------- xg = x @ WiT + bi via MFMA: [800][1500] ----------------
__global__ __launch_bounds__(256) void k_xg(float* ws, const void* xin, const void* wiin,
                                            const void* mask) {
  const int f32 = is_f32(mask);
  const unsigned short* X = f32 ? (const unsigned short*)(ws + O_XB)
                                : (const unsigned short*)xin;
  const unsigned short* W = f32 ? (const unsigned short*)(ws + O_WIB)
                                : (const unsigned short*)wiin;
  const int m0 = blockIdx.x * 16;
  const int w = threadIdx.x >> 6, lane = threadIdx.x & 63;
  const int n0 = blockIdx.y * 256 + w * 64;
  const int rA = lane & 15, kq = (lane >> 4) * 8;
  const unsigned short* ax = X + (long)(m0 + rA) * 768 + kq;
  const unsigned short* bx = W + (long)(n0 + rA) * 768 + kq;
  f32x4 acc[4] = {};
  for (int kt = 0; kt < 24; ++kt) {
    bf16x8 af = *(const bf16x8*)(ax + kt * 32);
#pragma unroll
    for (int nf = 0; nf < 4; ++nf) {
      bf16x8 bf = *(const bf16x8*)(bx + (long)nf * 16 * 768 + kt * 32);
      acc[nf] = __builtin_amdgcn_mfma_f32_16x16x32_bf16(af, bf, acc[nf], 0, 0, 0);
    }
  }
  const int rD = m0 + (lane >> 4) * 4, cD = lane & 15;
#pragma unroll
  for (int nf = 0; nf < 4; ++nf) {
    int col = n0 + nf * 16 + cD;
    if (col < 1500) {
      float bv = ws[O_BI + col];
#pragma unroll
      for (int q = 0; q < 4; ++q)
        ws[O_XG + (long)(rD + q) * 1500 + col] = acc[nf][q] + bv;
    }
  }
}

// ---------------- the recurrent scan: 40 WGs, concurrent-batched seq-sync (frozen R9) ----------------
__global__ __launch_bounds__(512, 2) void k_scan(float* ws) {
  const int w = blockIdx.x;            // 40
  const int b = w & 7, g = w >> 3;     // batch, gate-group/output-slice
  const int t = threadIdx.x;
  const int lane = t & 63, wid = t >> 6;
  const unsigned* W1 = (const unsigned*)(ws + O_WHT) + g * 45000;
  const unsigned* W2 = (const unsigned*)(ws + O_WTT) + g * 27000;
  const float* xg = ws + O_XG;
  ull* cs64 = (ull*)(ws + O_PUB) + (long)b * 1504;
  ull* c64  = (ull*)(ws + O_C64) + (long)b * 304;
  unsigned short* HN2 = (unsigned short*)(ws + O_HN2);
  unsigned short* HR2 = (unsigned short*)(ws + O_HR2);
  unsigned short* HS2 = (unsigned short*)(ws + O_HS2);

  // persistent weights in registers (f16 pairs along k)
  unsigned wA0[50], wA1[50], wB0[30], wB1[30];
  if (t < 450) {
#pragma unroll
    for (int i = 0; i < 50; ++i) { wA0[i] = W1[i * 450 + t]; wA1[i] = W1[22500 + i * 450 + t]; }
#pragma unroll
    for (int j = 0; j < 30; ++j) { wB0[j] = W2[j * 450 + t]; wB1[j] = W2[13500 + j * 450 + t]; }
  }
  // loop-invariant bias prefetch
  const float bhv = (t < 300) ? ws[O_BH + g * 300 + t] : 0.f;
  const float btv = (t < 60) ? ws[O_BT + g * 60 + t] : 0.f;

  __shared__ __align__(16) unsigned h2[152];     // h as f16 pairs
  __shared__ __align__(16) float cf[304];        // c(l-1) f32
  __shared__ __align__(16) float cfown[64];      // own c slice (skip self-poll)
  __shared__ __align__(16) float gatef[304];
  __shared__ __align__(16) float pacc[3][304];
  __shared__ __align__(16) float csL[1504];
  __shared__ __align__(16) float catf[912];
  __shared__ __align__(16) unsigned cat2[456];
  __shared__ __align__(16) float pacc2[15][64];

  if (t < 64) cfown[t] = 0.f;
  __syncthreads();

  const int o2a = t % 150, kca = t / 150;        // phase-A tile
  const int o2b = t % 30,  kcb = t / 30;         // phase-B tile

  for (int l = 0; l < 100; ++l) {
    const unsigned sl = (unsigned)l, sn = (unsigned)(l + 1);
    // prefetch xg early (L3 latency hides under the c-gather poll)
    float xgv = (t < 300) ? xg[((long)l * 8 + b) * 1500 + g * 300 + t] : 0.f;

    // ---- gather c(l-1): 150 threads, 2 CONCURRENT polls each; h=tanh(c) local ----
    if (t < 150) {
      const int ia = 2 * t;
      float va, vb;
      if (ia / 60 == g) {                        // own slice from LDS
        va = cfown[ia - g * 60]; vb = cfown[ia + 1 - g * 60];
      } else {
        ull wa = ld64(c64 + ia), wb = ld64(c64 + ia + 1);
        long it = 0;
        while ((((unsigned)wa != sl) || ((unsigned)wb != sl)) && ++it < (1L << 22)) {
          if ((unsigned)wa != sl) wa = ld64(c64 + ia);
          if ((unsigned)wb != sl) wb = ld64(c64 + ia + 1);
        }
        va = val64(wa); vb = val64(wb);
      }
      cf[ia] = va; cf[ia + 1] = vb;
      h2[t] = packf16(tanhf(va), tanhf(vb));
    }
    __syncthreads();

    // ---- phase A: gate slice = Wh_g@h + xg + bh; cumsoftmax; publish cs (seq l+1) ----
    if (t < 450) {
      float a0 = 0.f, a1 = 0.f;
      const unsigned* hp = h2 + kca * 50;
#pragma unroll
      for (int i = 0; i < 50; ++i) {
        unsigned hv = hp[i];
        a0 = dot2(wA0[i], hv, a0);
        a1 = dot2(wA1[i], hv, a1);
      }
      pacc[kca][2 * o2a] = a0; pacc[kca][2 * o2a + 1] = a1;
    }
    __syncthreads();
    if (t < 300)
      gatef[t] = pacc[0][t] + pacc[1][t] + pacc[2][t] + xgv + bhv;
    __syncthreads();
    if (g == 0) {
      if (t < 300) {
        float v = tanhf(gatef[t]);
        csL[t] = v;
        pub64(cs64 + t, v, sn);
      }
    } else if (wid == 0) {
      const int base = lane * 5;
      float e0 = 0.f, e1 = 0.f, e2 = 0.f, e3 = 0.f, e4 = 0.f, m = -3.0e38f;
      if (lane < 60) {
        e0 = gatef[base]; e1 = gatef[base + 1]; e2 = gatef[base + 2];
        e3 = gatef[base + 3]; e4 = gatef[base + 4];
        m = fmaxf(fmaxf(fmaxf(e0, e1), fmaxf(e2, e3)), e4);
      }
#pragma unroll
      for (int of = 32; of >= 1; of >>= 1) m = fmaxf(m, __shfl_xor(m, of, 64));
      float s0 = 0.f, s1 = 0.f, s2 = 0.f, s3 = 0.f, s4 = 0.f, tot = 0.f;
      if (lane < 60) {
        e0 = __expf(e0 - m); e1 = __expf(e1 - m); e2 = __expf(e2 - m);
        e3 = __expf(e3 - m); e4 = __expf(e4 - m);
        s0 = e0; s1 = s0 + e1; s2 = s1 + e2; s3 = s2 + e3; s4 = s3 + e4;
        tot = s4;
      }
      float sc = tot;
#pragma unroll
      for (int of = 1; of < 64; of <<= 1) {
        float u = __shfl_up(sc, of, 64);
        if (lane >= of) sc += u;
      }
      float total = __shfl(sc, 63);
      if (lane < 60) {
        float ex = sc - tot, inv = 1.f / total;
        float v0 = (ex + s0) * inv, v1 = (ex + s1) * inv, v2 = (ex + s2) * inv;
        float v3 = (ex + s3) * inv, v4 = (ex + s4) * inv;
        const int o0 = g * 300 + base;
        csL[o0] = v0; csL[o0 + 1] = v1; csL[o0 + 2] = v2; csL[o0 + 3] = v3; csL[o0 + 4] = v4;
        pub64(cs64 + o0 + 0, v0, sn);
        pub64(cs64 + o0 + 1, v1, sn);
        pub64(cs64 + o0 + 2, v2, sn);
        pub64(cs64 + o0 + 3, v3, sn);
        pub64(cs64 + o0 + 4, v4, sn);
      }
    }

    // ---- phase B: gather foreign cs with 3 CONCURRENT polls per thread ----
    {
      const int i0 = t, i1 = t + 512, i2 = t + 1024;
      const bool n0 = (i0 / 300) != g;
      const bool n1 = (i1 < 1500) && ((i1 / 300) != g);
      const bool n2 = (i2 < 1500) && ((i2 / 300) != g);
      ull w0 = n0 ? ld64(cs64 + i0) : 0;
      ull w1 = n1 ? ld64(cs64 + i1) : 0;
      ull w2 = n2 ? ld64(cs64 + i2) : 0;
      long it = 0;
      for (;;) {
        bool s0 = n0 && (unsigned)w0 != sn;
        bool s1 = n1 && (unsigned)w1 != sn;
        bool s2 = n2 && (unsigned)w2 != sn;
        if (!(s0 || s1 || s2) || ++it > (1L << 22)) break;
        if (s0) w0 = ld64(cs64 + i0);
        if (s1) w1 = ld64(cs64 + i1);
        if (s2) w2 = ld64(cs64 + i2);
      }
      if (n0) csL[i0] = val64(w0);
      if (n1) csL[i1] = val64(w1);
      if (n2) csL[i2] = val64(w2);
    }
    __syncthreads();
    if (t < 300) {
      float cgv = csL[t];
      float egi = 1.f - csL[300 + t];
      float rgi = csL[600 + t];
      float egc = 1.f - csL[900 + t];
      float rgc = csL[1200 + t];
      float cin = cf[t];
      float ovc = rgc * egc, upc = rgc - ovc, dnc = egc - ovc;
      float ovi = rgi * egi, upi = rgi - ovi, dni = egi - ovi;
      float sh = ovi * cin + ovc * cgv;
      float cre = upi * cin + upc * cgv + sh;
      float cner = dni * cin + dnc * cgv + sh;
      catf[t] = cre; catf[300 + t] = cner; catf[600 + t] = sh;
      if (g == 0) {
        long rb = ((long)l * 8 + b) * 320;
        HN2[rb + t] = bfbits(tanhf(cner));
        HR2[rb + t] = bfbits(tanhf(cre));
        HS2[rb + t] = bfbits(tanhf(sh));
      }
    } else if (g == 0 && t < 320) {
      long rb = ((long)l * 8 + b) * 320;
      HN2[rb + t] = 0; HR2[rb + t] = 0; HS2[rb + t] = 0;
    }
    __syncthreads();
    if (t < 450) cat2[t] = packf16(catf[2 * t], catf[2 * t + 1]);
    __syncthreads();
    if (t < 450) {
      float a0 = 0.f, a1 = 0.f;
      const unsigned* cp = cat2 + kcb * 30;
#pragma unroll
      for (int j = 0; j < 30; ++j) {
        unsigned cv = cp[j];
        a0 = dot2(wB0[j], cv, a0);
        a1 = dot2(wB1[j], cv, a1);
      }
      pacc2[kcb][2 * o2b] = a0; pacc2[kcb][2 * o2b + 1] = a1;
    }
    __syncthreads();
    if (t < 60) {
      float s = btv;
#pragma unroll
      for (int kc = 0; kc < 15; ++kc) s += pacc2[kc][t];
      pub64(c64 + g * 60 + t, s, sn);    // consumers derive h = tanh(c)
      cfown[t] = s;
    }
    __syncthreads();                     // cfown LDS handoff to next-step gather
  }
}

// ---------------- merged g3a + g3c via MFMA (blockIdx.z dispatch) ----------------
__global__ __launch_bounds__(256) void k_g3ac(float* ws, void* dout, const void* mask) {
  const int z = blockIdx.z;
  const int m0 = blockIdx.x * 16;
  const int w = threadIdx.x >> 6, lane = threadIdx.x & 63;
  const int n0 = blockIdx.y * 256 + w * 64;
  if (n0 >= 300) return;
  const int rA = lane & 15, kq = (lane >> 4) * 8;
  const int rD = m0 + (lane >> 4) * 4, cD = lane & 15;

  if (z < 2) {                 // ---- g3a: tG = tanh(cat(h_share,h_x)@WT + b) ----
    const int u = z;
    const int f32 = is_f32(mask);
    const unsigned short* A0 = (const unsigned short*)(ws + O_HS2);
    const unsigned short* A1 = (const unsigned short*)(ws + (u ? O_HR2 : O_HN2));
    const unsigned short* B = (const unsigned short*)(ws + O_WNB) + (long)u * 180000;
    const unsigned short* a0p = A0 + (long)(m0 + rA) * 320 + kq;
    const unsigned short* a1p = A1 + (long)(m0 + rA) * 320 + kq;
    const unsigned short* bp = B + (long)(n0 + rA) * 600 + kq;
    f32x4 acc[4] = {};
    for (int kt = 0; kt < 10; ++kt) {
      bf16x8 af = *(const bf16x8*)(a0p + kt * 32);
#pragma unroll
      for (int nf = 0; nf < 4; ++nf) {
        bf16x8 bf = *(const bf16x8*)(bp + (long)nf * 16 * 600 + kt * 32);
        acc[nf] = __builtin_amdgcn_mfma_f32_16x16x32_bf16(af, bf, acc[nf], 0, 0, 0);
      }
    }
    for (int kt = 0; kt < 10; ++kt) {
      bf16x8 af = *(const bf16x8*)(a1p + kt * 32);
#pragma unroll
      for (int nf = 0; nf < 4; ++nf) {
        bf16x8 bf = *(const bf16x8*)(bp + (long)nf * 16 * 600 + 300 + kt * 32);
        acc[nf] = __builtin_amdgcn_mfma_f32_16x16x32_bf16(af, bf, acc[nf], 0, 0, 0);
      }
    }
#pragma unroll
    for (int nf = 0; nf < 4; ++nf) {
      int col = n0 + nf * 16 + cD;
      if (col < 300) {
        float bv = ws[(u ? O_BR : O_BN) + col];
#pragma unroll
        for (int q = 0; q < 4; ++q) {
          float tv = tanhf(acc[nf][q] + bv);
          long idx = (long)(rD + q) * 300 + col;
          ws[O_TG + (long)u * 240000 + idx] = tv;
          if (u == 1) stout(dout, 1600000L + idx, tv, f32);
        }
      }
    }
  } else {                     // ---- g3c: start/end token projections a,b ----
    const int u = (z - 2) >> 1, proj = (z - 2) & 1;
    const unsigned short* A = (const unsigned short*)(ws + (u ? O_HR2 : O_HN2));
    const unsigned short* B = (const unsigned short*)(ws + O_W1B) + (long)u * 273600;
    const unsigned short* ap = A + (long)(m0 + rA) * 320 + kq;
    const unsigned short* bp = B + (long)(n0 + rA) * 912 + proj * 304 + kq;
    f32x4 acc[4] = {};
    for (int kt = 0; kt < 10; ++kt) {
      bf16x8 af = *(const bf16x8*)(ap + kt * 32);
#pragma unroll
      for (int nf = 0; nf < 4; ++nf) {
        bf16x8 bf = *(const bf16x8*)(bp + (long)nf * 16 * 912 + kt * 32);
        acc[nf] = __builtin_amdgcn_mfma_f32_16x16x32_bf16(af, bf, acc[nf], 0, 0, 0);
      }
    }
    const long dst = (proj ? O_BU : O_AU) + (long)u * 240000;
#pragma unroll
    for (int nf = 0; nf < 4; ++nf) {
      int col = n0 + nf * 16 + cD;
      if (col < 300) {
#pragma unroll
        for (int q = 0; q < 4; ++q)
          ws[dst + (long)(rD + q) * 300 + col] = acc[nf][q];
      }
    }
  }
}

// ---------------- max over L + global projection c (64 blocks: u, b, o-quarter) ----------------
__global__ __launch_bounds__(320) void k_g3b(float* ws) {
  const int u = blockIdx.x >> 5;
  const int b = (blockIdx.x >> 2) & 7;
  const int qr = blockIdx.x & 3;
  __shared__ float hs[304];
  const int o = threadIdx.x;
  const float* tg = ws + O_TG + (long)u * 240000;
  if (o < 300) {
    float m = -3e38f;
    for (int l = 0; l < 100; ++l) m = fmaxf(m, tg[((long)l * 8 + b) * 300 + o]);
    hs[o] = m;
  }
  __syncthreads();
  if (o < 75) {
    const int oo = qr * 75 + o;
    const float* w1 = ws + (u ? O_W1RT : O_W1NT);
    float acc = ws[(u ? O_B1R : O_B1N) + oo];
    for (int k = 0; k < 300; ++k) acc += hs[k] * w1[(long)(600 + k) * 300 + oo];
    ws[O_CU + (long)u * 2400 + b * 300 + oo] = acc;
  }
}

// ---------------- fused pair scoring: lane-per-pair, float4 LDS reads ----------------
template <int NOUT, bool TRI>
__device__ __forceinline__ void pair_body(float* ws, void* dout, int f32, int b,
    long obase, long uofs, long w2tofs, long b2ofs, long gbeofs, long cofs,
    float* aS, float* bS, float* miS, float* mjS) {
  const int i0 = blockIdx.x * 16, j0 = blockIdx.y * 32;
  const int t = threadIdx.x;
  for (int s = t; s < 16 * 300; s += 512) {
    int r = s / 300, o = s - r * 300;
    int i = i0 + r;
    float v = 0.f;
    if (i < 100) v = ws[O_AU + uofs + ((long)i * 8 + b) * 300 + o] + ws[cofs + b * 300 + o];
    aS[r * 304 + o] = v;
  }
  for (int s = t; s < 32 * 300; s += 512) {
    int r = s / 300, o = s - r * 300;
    int j = j0 + r;
    bS[r * 304 + o] = (j < 100) ? ws[O_BU + uofs + ((long)j * 8 + b) * 300 + o] : 0.f;
  }
  if (t < 16) miS[t] = (i0 + t < 100) ? ws[O_MASK + (i0 + t) * 8 + b] : 0.f;
  else if (t < 48) mjS[t - 16] = (j0 + t - 16 < 100) ? ws[O_MASK + (j0 + t - 16) * 8 + b] : 0.f;
  __syncthreads();
  const int wid = t >> 6, lane = t & 63;
  const int ii = wid * 2 + (lane >> 5);
  const int jj = lane & 31;
  const int i = i0 + ii, j = j0 + jj;
  if (i >= 100 || j >= 100) return;
  long base = obase + (((long)i * 100 + j) * 8 + b) * NOUT;
  // whole-wave lower-triangle skip (all 64 pair-slots have j < i)
  if (TRI && (j0 + 31 < i0 + wid * 2)) {
#pragma unroll
    for (int q = 0; q < NOUT; ++q) stout(dout, base + q, 0.f, f32);
    return;
  }
  const f32x4* ap4 = (const f32x4*)(aS + ii * 304);
  const f32x4* bp4 = (const f32x4*)(bS + jj * 304);
  float sum = 0.f, ssq = 0.f;
#pragma unroll 5
  for (int o4 = 0; o4 < 75; ++o4) {
    f32x4 av = ap4[o4], bv = bp4[o4];
    float v0 = av[0] + bv[0], v1 = av[1] + bv[1];
    float v2 = av[2] + bv[2], v3 = av[3] + bv[3];
    sum += v0; ssq = fmaf(v0, v0, ssq);
    sum += v1; ssq = fmaf(v1, v1, ssq);
    sum += v2; ssq = fmaf(v2, v2, ssq);
    sum += v3; ssq = fmaf(v3, v3, ssq);
  }
  float mean = sum * (1.f / 300.f);
  float inv = rsqrtf(ssq * (1.f / 300.f) - mean * mean + EPSV);
  float acc[NOUT];
#pragma unroll
  for (int q = 0; q < NOUT; ++q) acc[q] = 0.f;
  const float* gbe = ws + gbeofs;
  const float* w2t = ws + w2tofs;
#pragma unroll 2
  for (int o4 = 0; o4 < 75; ++o4) {
    f32x4 av = ap4[o4], bv = bp4[o4];
#pragma unroll
    for (int m2 = 0; m2 < 4; ++m2) {
      int o = 4 * o4 + m2;
      float v = av[m2] + bv[m2];
      float xn = fmaf((v - mean) * inv, gbe[2 * o], gbe[2 * o + 1]);
      float e = xn > 0.f ? xn : (__expf(xn) - 1.f);
#pragma unroll
      for (int q = 0; q < NOUT; ++q) acc[q] = fmaf(e, w2t[o * NOUT + q], acc[q]);
    }
  }
  float mv = miS[ii] * mjS[jj];
  if (TRI && j < i) mv = 0.f;
#pragma unroll
  for (int q = 0; q < NOUT; ++q) {
    float b2v = ws[b2ofs + q];
    stout(dout, base + q, mv / (1.f + __expf(-(acc[q] + b2v))), f32);
  }
}

__global__ __launch_bounds__(512) void k_pairs2(float* ws, void* dout, const void* mask) {
  __shared__ __align__(16) float aS[16 * 304];
  __shared__ __align__(16) float bS[32 * 304];
  __shared__ float miS[16], mjS[32];
  const int f32 = is_f32(mask);
  const int z = blockIdx.z;
  if (z < 8)
    pair_body<8, true>(ws, dout, f32, z, 0L, 0L, O_W2NT, O_B2N, O_GBEN, O_CU,
                       aS, bS, miS, mjS);
  else
    pair_body<12, false>(ws, dout, f32, z - 8, 640000L, 240000L, O_W2RT, O_B2R, O_GBER,
                         O_CU + 2400, aS, bS, miS, mjS);
}

// ---------------- host ----------------
extern "C" void kernel_launch(void* const* d_in, const int* in_sizes, int n_in,
                              void* d_out, int out_size, void* d_ws, size_t ws_size,
                              hipStream_t stream) {
  (void)in_sizes; (void)n_in; (void)out_size; (void)ws_size;
  float* ws = (float*)d_ws;
  const void* mask = d_in[1];
  k_prep<<<dim3(1604), dim3(256), 0, stream>>>(ws, mask,
      d_in[0], d_in[2], d_in[4], d_in[6],
      d_in[8], d_in[16], d_in[10], d_in[18],
      d_in[3], d_in[5], d_in[7],
      d_in[9], d_in[11], d_in[12], d_in[13], d_in[14], d_in[15],
      d_in[17], d_in[19], d_in[20], d_in[21], d_in[22], d_in[23]);
  k_xg<<<dim3(50, 6), dim3(256), 0, stream>>>(ws, d_in[0], d_in[2], mask);
  k_scan<<<dim3(40), dim3(512), 0, stream>>>(ws);
  k_g3ac<<<dim3(50, 2, 6), dim3(256), 0, stream>>>(ws, d_out, mask);
  k_g3b<<<dim3(64), dim3(320), 0, stream>>>(ws);
  k_pairs2<<<dim3(7, 4, 16), dim3(512), 0, stream>>>(ws, d_out, mask);
}